// Round 13
// baseline (81.071 us; speedup 1.0000x reference)
//
#include <hip/hip_runtime.h>
#include <hip/hip_bf16.h>

// CreateProposal (Faster-RCNN proposal layer), H=W=100, 9 anchors, stride 16.
// Pipeline (6 kernels):
//   k_prep    (8 blk)  : zero hist/meta
//   k_hist    (22 blk) : per-block LDS histogram -> global bins (atomics);
//                        LAST block computes bit threshold into meta[1]
//   k_csort   (8 blk)  : per-block compact of own 1/8 of candidates into LDS,
//                        register-resident bitonic sort (shfl intra-wave),
//                        write own 1024-key segment
//   k_rankdec (8 blk)  : stage all 8192 keys in LDS; exact global rank via 7
//                        LDS binary searches; decode+clip box into boxes[rank]
//   k_iou     (94x94)  : upper-tri: IoU bitmap M[6000][94]; lower-tri blocks
//                        write the 90000 anchors (free capacity)
//   k_scan    (1 blk)  : zero out-head; software-pipelined greedy scan,
//                        2 barriers/chunk, early-exit at 300

#define W100 100
#define HW10K 10000
#define NANCH 90000
#define PRE_TOPN 6000
#define POST_TOPN 300
#define PADN 8192
#define NLIST 8
#define LISTN 1024
#define NWORD 94           // ceil(6000/64)
#define NMS_TH 0.7f
#define NHB 22             // hist blocks (22*1024 >= 22500 float4)

typedef unsigned long long u64;
typedef unsigned u32;

__constant__ float c_anch[9][4] = {
    {-84.f,  -40.f,  99.f,  55.f},
    {-176.f, -88.f,  191.f, 103.f},
    {-360.f, -184.f, 375.f, 199.f},
    {-56.f,  -56.f,  71.f,  71.f},
    {-120.f, -120.f, 135.f, 135.f},
    {-248.f, -248.f, 263.f, 263.f},
    {-36.f,  -80.f,  51.f,  95.f},
    {-80.f,  -168.f, 95.f,  183.f},
    {-168.f, -344.f, 183.f, 359.f}
};

// meta layout: [1]=threshold, [6]=hist done

// ---------------- prep: zero hist/meta --------------------------------------
__global__ __launch_bounds__(1024)
void k_prep(u32* __restrict__ hist, u32* __restrict__ meta) {
    const int gtid = (int)blockIdx.x * 1024 + threadIdx.x;
    if (gtid < 8192) hist[gtid] = 0u;
    if (gtid < 8) meta[gtid] = 0u;
}

// -------- histogram (22 blk); last block computes threshold ------------------
__global__ __launch_bounds__(1024)
void k_hist(const float* __restrict__ scores, u32* __restrict__ hist,
            u32* __restrict__ meta) {
    __shared__ u32 lh[8192];
    __shared__ u32 wsum_s[16], wtail_s[16];
    __shared__ int s_last;
    const int tid = threadIdx.x;
    const int gtid = (int)blockIdx.x * 1024 + tid;

    for (int i = tid; i < 8192; i += 1024) lh[i] = 0u;
    __syncthreads();
    const float4* fg4 = (const float4*)(scores + 9 * HW10K);  // 22500 float4
    if (gtid < 22500) {
        float4 v = fg4[gtid];
        atomicAdd(&lh[__float_as_uint(v.x) >> 17], 1u);
        atomicAdd(&lh[__float_as_uint(v.y) >> 17], 1u);
        atomicAdd(&lh[__float_as_uint(v.z) >> 17], 1u);
        atomicAdd(&lh[__float_as_uint(v.w) >> 17], 1u);
    }
    __syncthreads();
    for (int i = tid; i < 8192; i += 1024) {
        u32 c = lh[i];
        if (c) atomicAdd(&hist[i], c);
    }
    __syncthreads();
    if (tid == 0) {
        u32 r = __hip_atomic_fetch_add(&meta[6], 1u, __ATOMIC_ACQ_REL,
                                       __HIP_MEMORY_SCOPE_AGENT);
        s_last = (r == (u32)NHB - 1u);
    }
    __syncthreads();
    if (!s_last) return;
    __builtin_amdgcn_fence(__ATOMIC_ACQUIRE, "agent");

    // ---- threshold via suffix scan (this block only) ----
    const int w = tid >> 6, lane = tid & 63;
    u32 h[8];
#pragma unroll
    for (int b = 0; b < 8; ++b)
        h[b] = __hip_atomic_load(&hist[tid * 8 + b], __ATOMIC_RELAXED,
                                 __HIP_MEMORY_SCOPE_AGENT);
    u32 gs = h[0] + h[1] + h[2] + h[3] + h[4] + h[5] + h[6] + h[7];
    u32 suf = gs;
#pragma unroll
    for (int d = 1; d < 64; d <<= 1) {
        u32 t = (u32)__shfl((int)suf, (lane + d) & 63);
        suf += (lane + d < 64) ? t : 0u;
    }
    if (lane == 0) wsum_s[w] = suf;
    __syncthreads();
    if (w == 0) {
        u32 v = (lane < 16) ? wsum_s[lane] : 0u;
        u32 s2 = v;
#pragma unroll
        for (int d = 1; d < 16; d <<= 1) {
            u32 t = (u32)__shfl((int)s2, (lane + d) & 63);
            s2 += (lane + d < 16) ? t : 0u;
        }
        if (lane < 16) wtail_s[lane] = s2 - v;
    }
    __syncthreads();
    u32 S = suf + wtail_s[w];
    if (S >= (u32)PRE_TOPN && S - gs < (u32)PRE_TOPN) {
        u32 run = S - gs;
        u32 T = (u32)tid * 8u;
        for (int b = 7; b >= 0; --b) {
            run += h[b];
            if (run >= (u32)PRE_TOPN) { T = (u32)tid * 8u + (u32)b; break; }
        }
        __hip_atomic_store(&meta[1], T << 17, __ATOMIC_RELAXED,
                           __HIP_MEMORY_SCOPE_AGENT);
    }
}

// -------- per-block compact + register-resident bitonic sort (8 blk) ---------
__global__ __launch_bounds__(1024)
void k_csort(const float* __restrict__ scores, u64* __restrict__ keys,
             const u32* __restrict__ meta) {
    __shared__ u64 s[LISTN];
    __shared__ u32 s_cnt;
    const int tid = threadIdx.x;
    const int gtid = (int)blockIdx.x * 1024 + tid;   // 0..8191

    for (int i = tid; i < LISTN; i += 1024) s[i] = 0ull;
    if (tid == 0) s_cnt = 0u;
    const u32 thr = meta[1];                         // cross-kernel: coherent
    __syncthreads();

    const float4* fg4 = (const float4*)(scores + 9 * HW10K);
    for (int i4 = gtid; i4 < 22500; i4 += 8192) {
        float4 v = fg4[i4];
        float sv[4] = {v.x, v.y, v.z, v.w};
#pragma unroll
        for (int e = 0; e < 4; ++e) {
            int f = 4 * i4 + e;                      // fg flat index [a][pos]
            u32 bits = __float_as_uint(sv[e]);
            if (bits >= thr) {
                int a = f / HW10K, pos = f - a * HW10K;
                u32 idx = (u32)(pos * 9 + a);
                u32 slot = atomicAdd(&s_cnt, 1u);    // LDS atomic
                if (slot < (u32)LISTN)
                    s[slot] = ((u64)bits << 32) | (u32)(~idx);
            }
        }
    }
    __syncthreads();

    // register-resident bitonic sort, DESCENDING (thread t owns element t).
    // step (k,j): partner t^j; new K = (asc^upper) ? min : max,
    // asc=(t&k)!=0, upper=(t&j)!=0.  j<=32 via shfl_xor; j>=64 via LDS.
    u64 K = s[tid];
#pragma unroll
    for (u32 k = 2; k <= 64; k <<= 1) {
        for (u32 j = k >> 1; j > 0; j >>= 1) {
            u64 Kp = __shfl_xor((unsigned long long)K, (int)j);
            bool sel = (((u32)tid & k) != 0u) ^ (((u32)tid & j) != 0u);
            K = sel ? (K < Kp ? K : Kp) : (K > Kp ? K : Kp);
        }
    }
    for (u32 k = 128; k <= 1024; k <<= 1) {
        for (u32 j = k >> 1; j >= 64; j >>= 1) {
            __syncthreads();                 // WAR guard vs previous reads
            s[tid] = K;
            __syncthreads();
            u64 Kp = s[tid ^ (int)j];
            bool sel = (((u32)tid & k) != 0u) ^ (((u32)tid & j) != 0u);
            K = sel ? (K < Kp ? K : Kp) : (K > Kp ? K : Kp);
        }
#pragma unroll
        for (u32 j = 32; j > 0; j >>= 1) {
            u64 Kp = __shfl_xor((unsigned long long)K, (int)j);
            bool sel = (((u32)tid & k) != 0u) ^ (((u32)tid & j) != 0u);
            K = sel ? (K < Kp ? K : Kp) : (K > Kp ? K : Kp);
        }
    }
    u64* seg = keys + (size_t)blockIdx.x * LISTN;
    seg[tid] = K;                            // coalesced, one store/thread
}

// -------- global rank via LDS binary searches + decode (8 blk) ---------------
__global__ __launch_bounds__(1024)
void k_rankdec(const u64* __restrict__ keys, const float* __restrict__ bbox,
               const float* __restrict__ im_info, float4* __restrict__ boxes) {
    __shared__ u64 lk[PADN];     // all 8 sorted lists, 64 KiB
    const int tid = threadIdx.x;
    const int gtid = (int)blockIdx.x * 1024 + tid;   // 0..8191
    for (int i = tid; i < PADN; i += 1024) lk[i] = keys[i];
    __syncthreads();

    const u64 e = lk[gtid];
    if (e == 0ull) return;                     // pad: rank >= C >= 6000
    const int l = (int)blockIdx.x;             // own list
    int rank = tid;                            // position in own (desc) list
#pragma unroll
    for (int l2 = 0; l2 < NLIST; ++l2) {
        if (l2 == l) continue;
        const u64* lst = lk + (size_t)l2 * LISTN;
        int lo = 0, hi = LISTN;                // count of elements > e
        while (lo < hi) {
            int mid = (lo + hi) >> 1;
            if (lst[mid] > e) lo = mid + 1; else hi = mid;
        }
        rank += lo;
    }
    if (rank >= PRE_TOPN) return;

    const u32 idx = ~((u32)e);
    int pos = (int)(idx / 9u);
    int a   = (int)(idx - (u32)pos * 9u);
    int y = pos / W100, x = pos - y * W100;
    float sx = (float)(x * 16), sy = (float)(y * 16);
    float ax1 = c_anch[a][0] + sx, ay1 = c_anch[a][1] + sy;
    float ax2 = c_anch[a][2] + sx, ay2 = c_anch[a][3] + sy;
    float w = ax2 - ax1 + 1.f, h = ay2 - ay1 + 1.f;
    float cx = ax1 + 0.5f * w,  cy = ay1 + 0.5f * h;
    float dx = bbox[(a * 4 + 0) * HW10K + pos];
    float dy = bbox[(a * 4 + 1) * HW10K + pos];
    float dw = bbox[(a * 4 + 2) * HW10K + pos];
    float dh = bbox[(a * 4 + 3) * HW10K + pos];
    float pcx = dx * w + cx, pcy = dy * h + cy;
    float pw = expf(dw) * w, ph = expf(dh) * h;
    float imH = im_info[0], imW = im_info[1];
    float x1 = pcx - 0.5f * pw, y1 = pcy - 0.5f * ph;
    float x2 = pcx + 0.5f * pw, y2 = pcy + 0.5f * ph;
    x1 = fminf(fmaxf(x1, 0.f), imW - 1.f);
    x2 = fminf(fmaxf(x2, 0.f), imW - 1.f);
    y1 = fminf(fmaxf(y1, 0.f), imH - 1.f);
    y2 = fminf(fmaxf(y2, 0.f), imH - 1.f);
    boxes[rank] = make_float4(x1, y1, x2, y2);
}

// -------- IoU bitmap (upper tri) + anchors (lower-tri blocks) ----------------
// M[i][w] bit k = ( IoU(box i, box 64w+k) > TH ) && (64w+k > i).
__global__ __launch_bounds__(64)
void k_iou(const float4* __restrict__ bx, u64* __restrict__ M,
           float4* __restrict__ anc_out) {
    const int rb = blockIdx.y, cb = blockIdx.x;
    const int tid = threadIdx.x;
    if (cb < rb) {                       // lower-tri: write anchors (free capacity)
        int lid = ((rb * (rb - 1)) >> 1) + cb;        // 0..4370
        int idx = lid * 64 + tid;
        if (idx < NANCH) {
            int a = idx % 9, pos = idx / 9;
            int y = pos / W100, x = pos - y * W100;
            float sx = (float)(x * 16), sy = (float)(y * 16);
            anc_out[idx] = make_float4(c_anch[a][0] + sx, c_anch[a][1] + sy,
                                       c_anch[a][2] + sx, c_anch[a][3] + sy);
        }
        return;
    }
    __shared__ float4 cbox[64];
    const int col0 = cb * 64;
    {
        int cj = col0 + tid;
        cbox[tid] = (cj < PRE_TOPN) ? bx[cj] : make_float4(0.f, 0.f, -2.f, -2.f);
    }
    __syncthreads();
    const int ri = rb * 64 + tid;
    if (ri >= PRE_TOPN) return;
    float4 b = bx[ri];
    float area = (b.z - b.x + 1.f) * (b.w - b.y + 1.f);
    u64 bits = 0ull;
    const int ncol = (col0 + 64 <= PRE_TOPN) ? 64 : (PRE_TOPN - col0);
#pragma unroll 8
    for (int k = 0; k < 64; ++k) {
        if (k >= ncol) break;
        float4 q = cbox[k];
        float qa = (q.z - q.x + 1.f) * (q.w - q.y + 1.f);
        float iw = fmaxf(fminf(b.z, q.z) - fmaxf(b.x, q.x) + 1.f, 0.f);
        float ih = fmaxf(fminf(b.w, q.w) - fmaxf(b.y, q.y) + 1.f, 0.f);
        float inter = iw * ih;
        float iou = inter / ((area + qa) - inter);
        if ((col0 + k > ri) && (iou > NMS_TH)) bits |= (1ull << k);
    }
    M[(size_t)ri * NWORD + cb] = bits;
}

// ------ greedy scan, software-pipelined, 2 barriers/chunk (1 blk, 1024) ------
__global__ __launch_bounds__(1024)
void k_scan(const u64* __restrict__ M, const float4* __restrict__ bx,
            float* __restrict__ out) {
    __shared__ u64 s_diag[2][64];
    __shared__ u64 s_supp[2];
    __shared__ u64 s_keptc;
    __shared__ int K[384];
    __shared__ int s_nK, s_nK2, s_rank;
    const int tid = threadIdx.x;
    const int lane = tid & 63;

    for (int i = tid; i < POST_TOPN * 5; i += 1024) out[i] = 0.f;
    if (tid < 64) s_diag[0][tid] = M[(size_t)tid * NWORD + 0];
    if (tid == 0) { s_supp[0] = 0ull; s_supp[1] = 0ull; s_nK = 0; s_rank = 0; }
    __syncthreads();

    for (int c = 0; c < NWORD; ++c) {
        const int par = c & 1, nxt = par ^ 1;
        const int w1 = c + 1;
        const int nK0 = s_nK;                 // stable: updated in fold phase,
                                              // readers separated by barrier B
        // prefetch word c+1 rows (kept | chunk-c | diag c+1)
        u64 kval = 0ull, cval = 0ull, dval = 0ull;
        if (w1 < NWORD) {
            if (tid < nK0) {
                kval = M[(size_t)K[tid] * NWORD + w1];
            } else if (tid >= 512 && tid < 576) {
                int j2 = w1 * 64 + (tid - 512);
                if (j2 < PRE_TOPN) dval = M[(size_t)j2 * NWORD + w1];
            } else if (tid >= 576 && tid < 640) {
                int j3 = c * 64 + (tid - 576);
                if (j3 < PRE_TOPN) cval = M[(size_t)j3 * NWORD + w1];
            }
        }
        // chase (wave 0), overlapped with the loads above
        if (tid < 64) {
            const int j = c * 64 + tid;
            const bool valid = j < PRE_TOPN;
            u64 m = s_diag[par][tid];
            u64 alive = __ballot(valid) & ~s_supp[par];
            u64 kept = 0ull;
            while (alive) {
                int k = (int)__builtin_ctzll(alive);
                kept |= (1ull << k);
                u32 mlo = (u32)__builtin_amdgcn_readlane((int)(u32)m, k);
                u32 mhi = (u32)__builtin_amdgcn_readlane((int)(u32)(m >> 32), k);
                alive &= ~(((u64)mhi << 32) | mlo);
                alive &= ~(1ull << k);
            }
            int r0 = s_rank;                 // read before lane-0 update
            if ((kept >> tid) & 1ull) {
                int rin = (int)__popcll(kept & ((1ull << tid) - 1ull));
                K[nK0 + rin] = j;
                int r = r0 + rin;
                if (r < POST_TOPN) {
                    float4 b = bx[j];
                    out[r * 5 + 0] = 0.f;
                    out[r * 5 + 1] = b.x; out[r * 5 + 2] = b.y;
                    out[r * 5 + 3] = b.z; out[r * 5 + 4] = b.w;
                }
            }
            if (tid == 0) {
                int nk = (int)__popcll(kept);
                s_keptc = kept;
                s_nK2 = nK0 + nk;
                s_rank = r0 + nk;
            }
        }
        __syncthreads();                     // barrier A
        if (s_rank >= POST_TOPN || w1 >= NWORD) break;   // uniform
        // fold phase: reset consumed supp, promote nK, OR prefetches into nxt
        if (tid == 0) { s_supp[par] = 0ull; s_nK = s_nK2; }
        u64 v = (tid < nK0) ? kval : 0ull;
        if (tid >= 576 && tid < 640 && ((s_keptc >> (tid - 576)) & 1ull)) v |= cval;
        v |= __shfl_xor((unsigned long long)v, 1);
        v |= __shfl_xor((unsigned long long)v, 2);
        v |= __shfl_xor((unsigned long long)v, 4);
        v |= __shfl_xor((unsigned long long)v, 8);
        v |= __shfl_xor((unsigned long long)v, 16);
        v |= __shfl_xor((unsigned long long)v, 32);
        if (lane == 0 && v) atomicOr(&s_supp[nxt], v);
        if (tid >= 512 && tid < 576) s_diag[nxt][tid - 512] = dval;
        __syncthreads();                     // barrier B
    }
}

// ---------------- launch ------------------------------------------------------
extern "C" void kernel_launch(void* const* d_in, const int* in_sizes, int n_in,
                              void* d_out, int out_size, void* d_ws, size_t ws_size,
                              hipStream_t stream) {
    const float* scores  = (const float*)d_in[0];   // (1,18,100,100)
    const float* bbox    = (const float*)d_in[1];   // (1,36,100,100)
    const float* im_info = (const float*)d_in[2];   // (3,)
    float* out = (float*)d_out;                     // 300*5 rows then 90000*4 anchors

    // workspace layout
    u64*    keys  = (u64*)d_ws;                                      // 65536 B
    float4* boxes = (float4*)((char*)d_ws + PADN * sizeof(u64));     // 96000 B
    u32*    meta  = (u32*)((char*)d_ws + 161536);                    // 32 B
    u32*    hist  = (u32*)((char*)d_ws + 163840);                    // 32768 B
    u64*    M     = (u64*)((char*)d_ws + 196608);                    // 4,512,000 B
    float4* anc   = (float4*)(out + POST_TOPN * 5);

    k_prep  <<<8, 1024, 0, stream>>>(hist, meta);
    k_hist  <<<NHB, 1024, 0, stream>>>(scores, hist, meta);
    k_csort <<<NLIST, 1024, 0, stream>>>(scores, keys, meta);
    k_rankdec<<<NLIST, 1024, 0, stream>>>(keys, bbox, im_info, boxes);
    dim3 g(NWORD, NWORD);
    k_iou   <<<g, 64, 0, stream>>>(boxes, M, anc);
    k_scan  <<<1, 1024, 0, stream>>>(M, boxes, out);
}

// Round 14
// 76.202 us; speedup vs baseline: 1.0639x; 1.0639x over previous
//
#include <hip/hip_runtime.h>
#include <hip/hip_bf16.h>

// CreateProposal (Faster-RCNN proposal layer), H=W=100, 9 anchors, stride 16.
// Pipeline (6 kernels) — round-12 structure, register-resident sort in k_csort:
//   k_prep    (88 blk) : zero hist/meta/out-head; write 90000 anchors
//   k_hist    (22 blk) : per-block LDS histogram -> global bins (atomics);
//                        LAST block computes bit threshold into meta[1]
//   k_csort   (8 blk)  : per-block compact of own 1/8 of candidates into LDS,
//                        register-resident bitonic sort (shfl intra-wave),
//                        write own 1024-key segment
//   k_rankdec (8 blk)  : stage all 8192 keys in LDS; exact global rank via 7
//                        LDS binary searches; decode+clip box into boxes[rank]
//   k_iou     (94x94)  : pairwise IoU bitmap M[6000][94], LDS-staged cols
//   k_scan    (1 blk)  : software-pipelined greedy scan, 2 barriers/chunk,
//                        early-exit at 300

#define W100 100
#define HW10K 10000
#define NANCH 90000
#define PRE_TOPN 6000
#define POST_TOPN 300
#define PADN 8192
#define NLIST 8
#define LISTN 1024
#define NWORD 94           // ceil(6000/64)
#define NMS_TH 0.7f
#define NHB 22             // hist blocks (22*1024 >= 22500 float4)

typedef unsigned long long u64;
typedef unsigned u32;

__constant__ float c_anch[9][4] = {
    {-84.f,  -40.f,  99.f,  55.f},
    {-176.f, -88.f,  191.f, 103.f},
    {-360.f, -184.f, 375.f, 199.f},
    {-56.f,  -56.f,  71.f,  71.f},
    {-120.f, -120.f, 135.f, 135.f},
    {-248.f, -248.f, 263.f, 263.f},
    {-36.f,  -80.f,  51.f,  95.f},
    {-80.f,  -168.f, 95.f,  183.f},
    {-168.f, -344.f, 183.f, 359.f}
};

// meta layout: [1]=threshold, [6]=hist done

// ---------------- prep: zero hist/meta/out-head, write anchors ---------------
__global__ __launch_bounds__(1024)
void k_prep(float4* __restrict__ anc_out, u32* __restrict__ hist,
            u32* __restrict__ meta, float* __restrict__ out) {
    const int gtid = (int)blockIdx.x * 1024 + threadIdx.x;
    if (gtid < 8192) hist[gtid] = 0u;
    if (gtid < POST_TOPN * 5) out[gtid] = 0.f;
    if (gtid < 8) meta[gtid] = 0u;
    if (gtid >= NANCH) return;
    int a = gtid % 9, pos = gtid / 9;
    int y = pos / W100, x = pos - y * W100;
    float sx = (float)(x * 16), sy = (float)(y * 16);
    anc_out[gtid] = make_float4(c_anch[a][0] + sx, c_anch[a][1] + sy,
                                c_anch[a][2] + sx, c_anch[a][3] + sy);
}

// -------- histogram (22 blk); last block computes threshold ------------------
__global__ __launch_bounds__(1024)
void k_hist(const float* __restrict__ scores, u32* __restrict__ hist,
            u32* __restrict__ meta) {
    __shared__ u32 lh[8192];
    __shared__ u32 wsum_s[16], wtail_s[16];
    __shared__ int s_last;
    const int tid = threadIdx.x;
    const int gtid = (int)blockIdx.x * 1024 + tid;

    for (int i = tid; i < 8192; i += 1024) lh[i] = 0u;
    __syncthreads();
    const float4* fg4 = (const float4*)(scores + 9 * HW10K);  // 22500 float4
    if (gtid < 22500) {
        float4 v = fg4[gtid];
        atomicAdd(&lh[__float_as_uint(v.x) >> 17], 1u);
        atomicAdd(&lh[__float_as_uint(v.y) >> 17], 1u);
        atomicAdd(&lh[__float_as_uint(v.z) >> 17], 1u);
        atomicAdd(&lh[__float_as_uint(v.w) >> 17], 1u);
    }
    __syncthreads();
    for (int i = tid; i < 8192; i += 1024) {
        u32 c = lh[i];
        if (c) atomicAdd(&hist[i], c);
    }
    __syncthreads();
    if (tid == 0) {
        u32 r = __hip_atomic_fetch_add(&meta[6], 1u, __ATOMIC_ACQ_REL,
                                       __HIP_MEMORY_SCOPE_AGENT);
        s_last = (r == (u32)NHB - 1u);
    }
    __syncthreads();
    if (!s_last) return;
    __builtin_amdgcn_fence(__ATOMIC_ACQUIRE, "agent");

    // ---- threshold via suffix scan (this block only) ----
    const int w = tid >> 6, lane = tid & 63;
    u32 h[8];
#pragma unroll
    for (int b = 0; b < 8; ++b)
        h[b] = __hip_atomic_load(&hist[tid * 8 + b], __ATOMIC_RELAXED,
                                 __HIP_MEMORY_SCOPE_AGENT);
    u32 gs = h[0] + h[1] + h[2] + h[3] + h[4] + h[5] + h[6] + h[7];
    u32 suf = gs;
#pragma unroll
    for (int d = 1; d < 64; d <<= 1) {
        u32 t = (u32)__shfl((int)suf, (lane + d) & 63);
        suf += (lane + d < 64) ? t : 0u;
    }
    if (lane == 0) wsum_s[w] = suf;
    __syncthreads();
    if (w == 0) {
        u32 v = (lane < 16) ? wsum_s[lane] : 0u;
        u32 s2 = v;
#pragma unroll
        for (int d = 1; d < 16; d <<= 1) {
            u32 t = (u32)__shfl((int)s2, (lane + d) & 63);
            s2 += (lane + d < 16) ? t : 0u;
        }
        if (lane < 16) wtail_s[lane] = s2 - v;
    }
    __syncthreads();
    u32 S = suf + wtail_s[w];
    if (S >= (u32)PRE_TOPN && S - gs < (u32)PRE_TOPN) {
        u32 run = S - gs;
        u32 T = (u32)tid * 8u;
        for (int b = 7; b >= 0; --b) {
            run += h[b];
            if (run >= (u32)PRE_TOPN) { T = (u32)tid * 8u + (u32)b; break; }
        }
        __hip_atomic_store(&meta[1], T << 17, __ATOMIC_RELAXED,
                           __HIP_MEMORY_SCOPE_AGENT);
    }
}

// -------- per-block compact + register-resident bitonic sort (8 blk) ---------
__global__ __launch_bounds__(1024)
void k_csort(const float* __restrict__ scores, u64* __restrict__ keys,
             const u32* __restrict__ meta) {
    __shared__ u64 s[LISTN];
    __shared__ u32 s_cnt;
    const int tid = threadIdx.x;
    const int gtid = (int)blockIdx.x * 1024 + tid;   // 0..8191

    for (int i = tid; i < LISTN; i += 1024) s[i] = 0ull;
    if (tid == 0) s_cnt = 0u;
    const u32 thr = meta[1];                         // cross-kernel: coherent
    __syncthreads();

    const float4* fg4 = (const float4*)(scores + 9 * HW10K);
    for (int i4 = gtid; i4 < 22500; i4 += 8192) {
        float4 v = fg4[i4];
        float sv[4] = {v.x, v.y, v.z, v.w};
#pragma unroll
        for (int e = 0; e < 4; ++e) {
            int f = 4 * i4 + e;                      // fg flat index [a][pos]
            u32 bits = __float_as_uint(sv[e]);
            if (bits >= thr) {
                int a = f / HW10K, pos = f - a * HW10K;
                u32 idx = (u32)(pos * 9 + a);
                u32 slot = atomicAdd(&s_cnt, 1u);    // LDS atomic
                if (slot < (u32)LISTN)
                    s[slot] = ((u64)bits << 32) | (u32)(~idx);
            }
        }
    }
    __syncthreads();

    // register-resident bitonic sort, DESCENDING (thread t owns element t).
    // step (k,j): partner t^j; K' = (asc^upper) ? min : max,
    // asc=(t&k)!=0, upper=(t&j)!=0.  j<=32 via shfl_xor; j>=64 via LDS.
    u64 K = s[tid];
#pragma unroll
    for (u32 k = 2; k <= 64; k <<= 1) {
        for (u32 j = k >> 1; j > 0; j >>= 1) {
            u64 Kp = __shfl_xor((unsigned long long)K, (int)j);
            bool sel = (((u32)tid & k) != 0u) ^ (((u32)tid & j) != 0u);
            K = sel ? (K < Kp ? K : Kp) : (K > Kp ? K : Kp);
        }
    }
    for (u32 k = 128; k <= 1024; k <<= 1) {
        for (u32 j = k >> 1; j >= 64; j >>= 1) {
            __syncthreads();                 // WAR guard vs previous reads
            s[tid] = K;
            __syncthreads();
            u64 Kp = s[tid ^ (int)j];
            bool sel = (((u32)tid & k) != 0u) ^ (((u32)tid & j) != 0u);
            K = sel ? (K < Kp ? K : Kp) : (K > Kp ? K : Kp);
        }
#pragma unroll
        for (u32 j = 32; j > 0; j >>= 1) {
            u64 Kp = __shfl_xor((unsigned long long)K, (int)j);
            bool sel = (((u32)tid & k) != 0u) ^ (((u32)tid & j) != 0u);
            K = sel ? (K < Kp ? K : Kp) : (K > Kp ? K : Kp);
        }
    }
    u64* seg = keys + (size_t)blockIdx.x * LISTN;
    seg[tid] = K;                            // coalesced, one store/thread
}

// -------- global rank via LDS binary searches + decode (8 blk) ---------------
__global__ __launch_bounds__(1024)
void k_rankdec(const u64* __restrict__ keys, const float* __restrict__ bbox,
               const float* __restrict__ im_info, float4* __restrict__ boxes) {
    __shared__ u64 lk[PADN];     // all 8 sorted lists, 64 KiB
    const int tid = threadIdx.x;
    const int gtid = (int)blockIdx.x * 1024 + tid;   // 0..8191
    for (int i = tid; i < PADN; i += 1024) lk[i] = keys[i];
    __syncthreads();

    const u64 e = lk[gtid];
    if (e == 0ull) return;                     // pad: rank >= C >= 6000
    const int l = (int)blockIdx.x;             // own list
    int rank = tid;                            // position in own (desc) list
#pragma unroll
    for (int l2 = 0; l2 < NLIST; ++l2) {
        if (l2 == l) continue;
        const u64* lst = lk + (size_t)l2 * LISTN;
        int lo = 0, hi = LISTN;                // count of elements > e
        while (lo < hi) {
            int mid = (lo + hi) >> 1;
            if (lst[mid] > e) lo = mid + 1; else hi = mid;
        }
        rank += lo;
    }
    if (rank >= PRE_TOPN) return;

    const u32 idx = ~((u32)e);
    int pos = (int)(idx / 9u);
    int a   = (int)(idx - (u32)pos * 9u);
    int y = pos / W100, x = pos - y * W100;
    float sx = (float)(x * 16), sy = (float)(y * 16);
    float ax1 = c_anch[a][0] + sx, ay1 = c_anch[a][1] + sy;
    float ax2 = c_anch[a][2] + sx, ay2 = c_anch[a][3] + sy;
    float w = ax2 - ax1 + 1.f, h = ay2 - ay1 + 1.f;
    float cx = ax1 + 0.5f * w,  cy = ay1 + 0.5f * h;
    float dx = bbox[(a * 4 + 0) * HW10K + pos];
    float dy = bbox[(a * 4 + 1) * HW10K + pos];
    float dw = bbox[(a * 4 + 2) * HW10K + pos];
    float dh = bbox[(a * 4 + 3) * HW10K + pos];
    float pcx = dx * w + cx, pcy = dy * h + cy;
    float pw = expf(dw) * w, ph = expf(dh) * h;
    float imH = im_info[0], imW = im_info[1];
    float x1 = pcx - 0.5f * pw, y1 = pcy - 0.5f * ph;
    float x2 = pcx + 0.5f * pw, y2 = pcy + 0.5f * ph;
    x1 = fminf(fmaxf(x1, 0.f), imW - 1.f);
    x2 = fminf(fmaxf(x2, 0.f), imW - 1.f);
    y1 = fminf(fmaxf(y1, 0.f), imH - 1.f);
    y2 = fminf(fmaxf(y2, 0.f), imH - 1.f);
    boxes[rank] = make_float4(x1, y1, x2, y2);
}

// ---------------- pairwise suppression bitmap (grid, LDS cols) ---------------
// M[i][w] bit k = ( IoU(box i, box 64w+k) > TH ) && (64w+k > i), upper tri only.
__global__ __launch_bounds__(64)
void k_iou(const float4* __restrict__ bx, u64* __restrict__ M) {
    const int rb = blockIdx.y, cb = blockIdx.x;
    if (cb < rb) return;
    __shared__ float4 cbox[64];
    const int tid = threadIdx.x;
    const int col0 = cb * 64;
    {
        int cj = col0 + tid;
        cbox[tid] = (cj < PRE_TOPN) ? bx[cj] : make_float4(0.f, 0.f, -2.f, -2.f);
    }
    __syncthreads();
    const int ri = rb * 64 + tid;
    if (ri >= PRE_TOPN) return;
    float4 b = bx[ri];
    float area = (b.z - b.x + 1.f) * (b.w - b.y + 1.f);
    u64 bits = 0ull;
    const int ncol = (col0 + 64 <= PRE_TOPN) ? 64 : (PRE_TOPN - col0);
#pragma unroll 8
    for (int k = 0; k < 64; ++k) {
        if (k >= ncol) break;
        float4 q = cbox[k];
        float qa = (q.z - q.x + 1.f) * (q.w - q.y + 1.f);
        float iw = fmaxf(fminf(b.z, q.z) - fmaxf(b.x, q.x) + 1.f, 0.f);
        float ih = fmaxf(fminf(b.w, q.w) - fmaxf(b.y, q.y) + 1.f, 0.f);
        float inter = iw * ih;
        float iou = inter / ((area + qa) - inter);
        if ((col0 + k > ri) && (iou > NMS_TH)) bits |= (1ull << k);
    }
    M[(size_t)ri * NWORD + cb] = bits;
}

// ------ greedy scan, software-pipelined, 2 barriers/chunk (1 blk, 1024) ------
__global__ __launch_bounds__(1024)
void k_scan(const u64* __restrict__ M, const float4* __restrict__ bx,
            float* __restrict__ out) {
    __shared__ u64 s_diag[2][64];
    __shared__ u64 s_supp[2];
    __shared__ u64 s_keptc;
    __shared__ int K[384];
    __shared__ int s_nK, s_nK2, s_rank;
    const int tid = threadIdx.x;
    const int lane = tid & 63;

    if (tid < 64) s_diag[0][tid] = M[(size_t)tid * NWORD + 0];
    if (tid == 0) { s_supp[0] = 0ull; s_supp[1] = 0ull; s_nK = 0; s_rank = 0; }
    __syncthreads();

    for (int c = 0; c < NWORD; ++c) {
        const int par = c & 1, nxt = par ^ 1;
        const int w1 = c + 1;
        const int nK0 = s_nK;                 // stable: updated in fold phase,
                                              // readers separated by barrier B
        // prefetch word c+1 rows (kept | chunk-c | diag c+1)
        u64 kval = 0ull, cval = 0ull, dval = 0ull;
        if (w1 < NWORD) {
            if (tid < nK0) {
                kval = M[(size_t)K[tid] * NWORD + w1];
            } else if (tid >= 512 && tid < 576) {
                int j2 = w1 * 64 + (tid - 512);
                if (j2 < PRE_TOPN) dval = M[(size_t)j2 * NWORD + w1];
            } else if (tid >= 576 && tid < 640) {
                int j3 = c * 64 + (tid - 576);
                if (j3 < PRE_TOPN) cval = M[(size_t)j3 * NWORD + w1];
            }
        }
        // chase (wave 0), overlapped with the loads above
        if (tid < 64) {
            const int j = c * 64 + tid;
            const bool valid = j < PRE_TOPN;
            u64 m = s_diag[par][tid];
            u64 alive = __ballot(valid) & ~s_supp[par];
            u64 kept = 0ull;
            while (alive) {
                int k = (int)__builtin_ctzll(alive);
                kept |= (1ull << k);
                u32 mlo = (u32)__builtin_amdgcn_readlane((int)(u32)m, k);
                u32 mhi = (u32)__builtin_amdgcn_readlane((int)(u32)(m >> 32), k);
                alive &= ~(((u64)mhi << 32) | mlo);
                alive &= ~(1ull << k);
            }
            int r0 = s_rank;                 // read before lane-0 update
            if ((kept >> tid) & 1ull) {
                int rin = (int)__popcll(kept & ((1ull << tid) - 1ull));
                K[nK0 + rin] = j;
                int r = r0 + rin;
                if (r < POST_TOPN) {
                    float4 b = bx[j];
                    out[r * 5 + 0] = 0.f;
                    out[r * 5 + 1] = b.x; out[r * 5 + 2] = b.y;
                    out[r * 5 + 3] = b.z; out[r * 5 + 4] = b.w;
                }
            }
            if (tid == 0) {
                int nk = (int)__popcll(kept);
                s_keptc = kept;
                s_nK2 = nK0 + nk;
                s_rank = r0 + nk;
            }
        }
        __syncthreads();                     // barrier A
        if (s_rank >= POST_TOPN || w1 >= NWORD) break;   // uniform
        // fold phase: reset consumed supp, promote nK, OR prefetches into nxt
        if (tid == 0) { s_supp[par] = 0ull; s_nK = s_nK2; }
        u64 v = (tid < nK0) ? kval : 0ull;
        if (tid >= 576 && tid < 640 && ((s_keptc >> (tid - 576)) & 1ull)) v |= cval;
        v |= __shfl_xor((unsigned long long)v, 1);
        v |= __shfl_xor((unsigned long long)v, 2);
        v |= __shfl_xor((unsigned long long)v, 4);
        v |= __shfl_xor((unsigned long long)v, 8);
        v |= __shfl_xor((unsigned long long)v, 16);
        v |= __shfl_xor((unsigned long long)v, 32);
        if (lane == 0 && v) atomicOr(&s_supp[nxt], v);
        if (tid >= 512 && tid < 576) s_diag[nxt][tid - 512] = dval;
        __syncthreads();                     // barrier B
    }
}

// ---------------- launch ------------------------------------------------------
extern "C" void kernel_launch(void* const* d_in, const int* in_sizes, int n_in,
                              void* d_out, int out_size, void* d_ws, size_t ws_size,
                              hipStream_t stream) {
    const float* scores  = (const float*)d_in[0];   // (1,18,100,100)
    const float* bbox    = (const float*)d_in[1];   // (1,36,100,100)
    const float* im_info = (const float*)d_in[2];   // (3,)
    float* out = (float*)d_out;                     // 300*5 rows then 90000*4 anchors

    // workspace layout
    u64*    keys  = (u64*)d_ws;                                      // 65536 B
    float4* boxes = (float4*)((char*)d_ws + PADN * sizeof(u64));     // 96000 B
    u32*    meta  = (u32*)((char*)d_ws + 161536);                    // 32 B
    u32*    hist  = (u32*)((char*)d_ws + 163840);                    // 32768 B
    u64*    M     = (u64*)((char*)d_ws + 196608);                    // 4,512,000 B
    float4* anc   = (float4*)(out + POST_TOPN * 5);

    k_prep  <<<88, 1024, 0, stream>>>(anc, hist, meta, out);
    k_hist  <<<NHB, 1024, 0, stream>>>(scores, hist, meta);
    k_csort <<<NLIST, 1024, 0, stream>>>(scores, keys, meta);
    k_rankdec<<<NLIST, 1024, 0, stream>>>(keys, bbox, im_info, boxes);
    dim3 g(NWORD, NWORD);
    k_iou   <<<g, 64, 0, stream>>>(boxes, M);
    k_scan  <<<1, 1024, 0, stream>>>(M, boxes, out);
}